// Round 5
// baseline (1927.212 us; speedup 1.0000x reference)
//
#include <hip/hip_runtime.h>
#include <hip/hip_bf16.h>

#define HH 96
#define WW 96
#define NPX 9216          // HH*WW
#define NC 21             // classes

// bilateral MFMA tiling: block=256 (4 waves); wave = 4 n-tiles of 32 j = 128 j;
// block = 512 j; i chunked 32x288; K-steps of 16
#define CH 288
#define NKS 18            // CH/16
#define NIB 32            // i-chunks (grid.y)
#define JBX 18            // j-blocks (grid.x), 18*512=9216
#define NT 4

// rowsum tiling (R4)
#define RNI 144
#define RCH 64

// truncated separable gaussian: radius 24
#define RAD2 24
#define TAPS2 49

typedef __attribute__((ext_vector_type(8))) short s8v;
typedef __attribute__((ext_vector_type(16))) float f16v;

// normalized separable 1D gaussian taps g[|d|] (exp(-d^2/72)/S, S=15.03977)
__device__ const float GN[36] = {
    6.64904e-02f, 6.55733e-02f, 6.28973e-02f, 5.86776e-02f, 5.32413e-02f,
    4.69853e-02f, 4.03286e-02f, 3.36665e-02f, 2.73351e-02f, 2.15863e-02f,
    1.65795e-02f, 1.23852e-02f, 8.99851e-03f, 6.35877e-03f, 4.37031e-03f,
    2.92139e-03f, 1.89933e-03f, 1.20102e-03f, 7.38645e-04f, 4.41830e-04f,
    2.57057e-04f, 1.45461e-04f, 8.00452e-05f, 4.28451e-05f, 2.23052e-05f,
    1.12939e-05f, 5.56182e-06f, 2.66396e-06f, 1.24101e-06f, 5.62291e-07f,
    2.47787e-07f, 1.06203e-07f, 4.42716e-08f, 1.79497e-08f, 7.07818e-09f,
    2.71479e-09f
};

__device__ __forceinline__ bool is_bf16(const void* kstd_raw){
    return (((const unsigned int*)kstd_raw)[0] & 0xFFFFu) != 0u;
}
__device__ __forceinline__ float ld_in(const void* p, int i, bool bf){
    if (bf){
        unsigned int u = ((unsigned int)((const unsigned short*)p)[i]) << 16;
        return __uint_as_float(u);
    }
    return ((const float*)p)[i];
}
__device__ __forceinline__ unsigned short f2bf(float f){
    unsigned int u = __float_as_uint(f);
    unsigned int r = u + 0x7FFFu + ((u >> 16) & 1u);   // RNE
    return (unsigned short)(r >> 16);
}

// ---------- setup: features (+|f|^2 in slot5), U=log(clip(u)), q0=softmax(U), zero qbf/nacc ----------
__global__ __launch_bounds__(256) void setup_kernel(const void* __restrict__ unary_raw,
                                                    const void* __restrict__ ref_raw,
                                                    const void* __restrict__ kstd_raw,
                                                    float* __restrict__ feat,
                                                    float* __restrict__ U, float* __restrict__ q,
                                                    float* __restrict__ qbf,
                                                    float* __restrict__ nacc){
    int i = blockIdx.x*256 + threadIdx.x;
    if (i >= NPX) return;
    bool bf = is_bf16(kstd_raw);
    const float SCL = 0.84932180028801907f; // sqrt(0.5*log2(e))
    int y = i / WW, x = i - y*WW;
    float f0 = (float)y * (SCL / ld_in(kstd_raw, 0, bf));
    float f1 = (float)x * (SCL / ld_in(kstd_raw, 1, bf));
    float f2 = ld_in(ref_raw, 0*NPX+i, bf) * (SCL / ld_in(kstd_raw, 2, bf));
    float f3 = ld_in(ref_raw, 1*NPX+i, bf) * (SCL / ld_in(kstd_raw, 3, bf));
    float f4 = ld_in(ref_raw, 2*NPX+i, bf) * (SCL / ld_in(kstd_raw, 4, bf));
    feat[i*8+0] = f0; feat[i*8+1] = f1; feat[i*8+2] = f2; feat[i*8+3] = f3; feat[i*8+4] = f4;
    feat[i*8+5] = f0*f0 + f1*f1 + f2*f2 + f3*f3 + f4*f4;
    feat[i*8+6] = 0.f; feat[i*8+7] = 0.f;
    nacc[i] = 0.f;

    float u[NC]; float m = -1e30f;
    #pragma unroll
    for (int c = 0; c < NC; ++c){
        float v = ld_in(unary_raw, c*NPX+i, bf);
        v = fminf(fmaxf(v, 1e-5f), 1.0f);
        float lg = logf(v);
        U[c*NPX+i] = lg;
        u[c] = lg;
        m = fmaxf(m, lg);
        qbf[c*NPX+i] = 0.f;
    }
    float s = 0.f;
    #pragma unroll
    for (int c = 0; c < NC; ++c){ u[c] = expf(u[c]-m); s += u[c]; }
    float inv = 1.f/s;
    #pragma unroll
    for (int c = 0; c < NC; ++c) q[c*NPX+i] = u[c]*inv;
}

// ---------- rowsum of K (for norm), dot-form ----------
__global__ __launch_bounds__(256) void rowsum_kernel(const float* __restrict__ feat,
                                                     float* __restrict__ nacc){
    __shared__ __align__(16) float s_feat[RNI*8];
    int tid = threadIdx.x;
    int i0 = blockIdx.y * RNI;
    for (int s = tid; s < RNI*2; s += 256)
        ((float4*)s_feat)[s] = ((const float4*)(feat + i0*8))[s];
    __syncthreads();
    int j = blockIdx.x*256 + tid;
    float4 fj = *(const float4*)(feat + j*8);
    float2 fj45 = *(const float2*)(feat + j*8 + 4);
    float fj4 = fj45.x, sqj = fj45.y;
    float a = 0.f;
    #pragma unroll 4
    for (int ii = 0; ii < RNI; ++ii){
        const float* sf = s_feat + ii*8;
        float4 f0 = *(const float4*)sf;
        float2 f45 = *(const float2*)(sf+4);
        float dot = fj.x*f0.x + fj.y*f0.y + fj.z*f0.z + fj.w*f0.w + fj4*f45.x;
        float d2 = fmaxf(sqj + f45.y - 2.0f*dot, 0.f);
        a += exp2f(-d2);
    }
    atomicAdd(&nacc[j], a);
}

__global__ __launch_bounds__(256) void normfin_kernel(const float* __restrict__ nacc,
                                                      float* __restrict__ rnorm){
    int j = blockIdx.x*256 + threadIdx.x;
    if (j >= NPX) return;
    rnorm[j] = 1.0f / (sqrtf(nacc[j]) + 1e-8f);
}

// ---------- fused separable spatial conv: one block per channel, LDS intermediate ----------
__global__ __launch_bounds__(256) void spatial_kernel(const float* __restrict__ q,
                                                      float* __restrict__ qsf){
    __shared__ float s_img[HH*(WW+1)];   // +1 stride kills column bank conflicts
    int c = blockIdx.x;
    int tid = threadIdx.x;
    const float* img = q + c*NPX;
    for (int p = tid; p < NPX; p += 256){
        int y = p / WW, x = p - y*WW;
        const float* row = img + y*WW;
        int tlo = max(0, RAD2 - x);
        int thi = min(TAPS2-1, RAD2 + (WW-1) - x);
        float a = 0.f;
        for (int t = tlo; t <= thi; ++t) a += GN[abs(t-RAD2)]*row[x + t - RAD2];
        s_img[y*(WW+1)+x] = a;
    }
    __syncthreads();
    for (int p = tid; p < NPX; p += 256){
        int y = p / WW, x = p - y*WW;
        int tlo = max(0, RAD2 - y);
        int thi = min(TAPS2-1, RAD2 + (HH-1) - y);
        float a = 0.f;
        for (int t = tlo; t <= thi; ++t) a += GN[abs(t-RAD2)]*s_img[(y + t - RAD2)*(WW+1) + x];
        qsf[c*NPX+p] = a;
    }
}

// ---------- dense bilateral via MFMA: qbf[c,j] += sum_i w(i,j) * tmp[c,i], w in bf16 ----------
__global__ __launch_bounds__(256) void bilateral_kernel(const float* __restrict__ q,
                                                        const float* __restrict__ feat,
                                                        const float* __restrict__ rnorm,
                                                        float* __restrict__ qbf){
    __shared__ __align__(16) float s_feat[CH*8];
    __shared__ __align__(16) unsigned short s_tmpA[CH*32];  // [i>>3][c(32)][i&7] bf16
    int tid = threadIdx.x;
    int i0 = blockIdx.y * CH;
    for (int v = tid; v < CH*2; v += 256)
        ((float4*)s_feat)[v] = ((const float4*)(feat + (size_t)i0*8))[v];
    for (int e = tid; e < 32*CH; e += 256){
        int c = e / CH; int i = e - c*CH;
        float val = (c < NC) ? q[c*NPX + i0 + i] * rnorm[i0 + i] : 0.f;
        s_tmpA[(i>>3)*256 + c*8 + (i&7)] = f2bf(val);
    }
    __syncthreads();

    int lane = tid & 63;
    int wv = tid >> 6;
    int jwb = blockIdx.x*512 + wv*128;
    int jl = lane & 31;
    int half = lane >> 5;

    float4 fj03[NT]; float fj4[NT], sqj[NT];
    #pragma unroll
    for (int n = 0; n < NT; ++n){
        const float* fp = feat + (size_t)(jwb + n*32 + jl)*8;
        fj03[n] = *(const float4*)fp;
        float2 t = *(const float2*)(fp+4);
        fj4[n] = t.x; sqj[n] = t.y;
    }
    f16v acc[NT];
    #pragma unroll
    for (int n = 0; n < NT; ++n)
        #pragma unroll
        for (int r = 0; r < 16; ++r) acc[n][r] = 0.f;

    for (int kc = 0; kc < NKS; ++kc){
        s8v afrag = *(const s8v*)(s_tmpA + (kc*2 + half)*256 + jl*8);
        union { s8v v; unsigned short u[8]; } bfr[NT];
        #pragma unroll
        for (int idx = 0; idx < 8; ++idx){
            const float* sf = s_feat + (kc*16 + half*8 + idx)*8;
            float4 f03 = *(const float4*)sf;
            float2 f45 = *(const float2*)(sf+4);
            #pragma unroll
            for (int n = 0; n < NT; ++n){
                float dot = fj03[n].x*f03.x + fj03[n].y*f03.y + fj03[n].z*f03.z
                          + fj03[n].w*f03.w + fj4[n]*f45.x;
                float d2 = fmaxf(sqj[n] + f45.y - 2.0f*dot, 0.f);
                bfr[n].u[idx] = f2bf(exp2f(-d2));
            }
        }
        #pragma unroll
        for (int n = 0; n < NT; ++n)
            acc[n] = __builtin_amdgcn_mfma_f32_32x32x16_bf16(afrag, bfr[n].v, acc[n], 0, 0, 0);
    }
    // C layout: col=j=lane&31, row=c=(reg&3)+8*(reg>>2)+4*(lane>>5)
    #pragma unroll
    for (int n = 0; n < NT; ++n){
        int j = jwb + n*32 + jl;
        #pragma unroll
        for (int r = 0; r < 16; ++r){
            int c = (r&3) + 8*(r>>2) + 4*half;
            if (c < NC) atomicAdd(&qbf[c*NPX + j], acc[n][r]);
        }
    }
}

// ---------- q_hat = U + 4*qbf*rnorm_j + 2*qsf ; softmax; zero qbf for next iter ----------
__global__ __launch_bounds__(256) void combine_kernel(const float* __restrict__ U,
                                                      float* __restrict__ qbf,
                                                      const float* __restrict__ qsf,
                                                      const float* __restrict__ rnorm,
                                                      float* __restrict__ qn,
                                                      void* __restrict__ outp,
                                                      const void* __restrict__ kstd_raw){
    int j = blockIdx.x*256 + threadIdx.x;
    if (j >= NPX) return;
    float rn = rnorm[j];
    float h[NC]; float m = -1e30f;
    #pragma unroll
    for (int c = 0; c < NC; ++c){
        float v = U[c*NPX+j] + 4.0f*qbf[c*NPX+j]*rn + 2.0f*qsf[c*NPX+j];
        qbf[c*NPX+j] = 0.f;
        h[c] = v; m = fmaxf(m, v);
    }
    float s = 0.f;
    #pragma unroll
    for (int c = 0; c < NC; ++c){ h[c] = expf(h[c]-m); s += h[c]; }
    float inv = 1.f/s;
    bool bf = outp ? is_bf16(kstd_raw) : false;
    #pragma unroll
    for (int c = 0; c < NC; ++c){
        float v = h[c]*inv;
        qn[c*NPX+j] = v;
        if (outp){
            if (bf) ((__hip_bfloat16*)outp)[c*NPX+j] = __float2bfloat16(v);
            else    ((float*)outp)[c*NPX+j] = v;
        }
    }
}

extern "C" void kernel_launch(void* const* d_in, const int* in_sizes, int n_in,
                              void* d_out, int out_size, void* d_ws, size_t ws_size,
                              hipStream_t stream) {
    const void* unary_raw = d_in[0];
    const void* ref_raw   = d_in[1];
    const void* kstd_raw  = d_in[2];

    float* w = (float*)d_ws;
    float* feat  = w; w += NPX*8;
    float* U     = w; w += NC*NPX;
    float* qA    = w; w += NC*NPX;
    float* qB    = w; w += NC*NPX;
    float* qsf   = w; w += NC*NPX;
    float* qbf   = w; w += NC*NPX;
    float* nacc  = w; w += NPX;
    float* rnorm = w; w += NPX;

    hipLaunchKernelGGL(setup_kernel, dim3(36), dim3(256), 0, stream,
                       unary_raw, ref_raw, kstd_raw, feat, U, qA, qbf, nacc);
    hipLaunchKernelGGL(rowsum_kernel, dim3(36, RCH), dim3(256), 0, stream, feat, nacc);
    hipLaunchKernelGGL(normfin_kernel, dim3(36), dim3(256), 0, stream, nacc, rnorm);

    float* qc = qA; float* qn = qB;
    for (int it = 0; it < 5; ++it){
        hipLaunchKernelGGL(spatial_kernel, dim3(NC), dim3(256), 0, stream, qc, qsf);
        hipLaunchKernelGGL(bilateral_kernel, dim3(JBX, NIB), dim3(256), 0, stream, qc, feat, rnorm, qbf);
        hipLaunchKernelGGL(combine_kernel, dim3(36), dim3(256), 0, stream,
                           U, qbf, qsf, rnorm, qn, (it == 4) ? d_out : (void*)nullptr, kstd_raw);
        float* tswap = qc; qc = qn; qn = tswap;
    }
}

// Round 6
// 535.371 us; speedup vs baseline: 3.5998x; 3.5998x over previous
//
#include <hip/hip_runtime.h>
#include <hip/hip_bf16.h>

#define HH 96
#define WW 96
#define NPX 9216          // HH*WW
#define NC 21             // classes

// bilateral MFMA tiling: block=256 (4 waves); wave = 4 n-tiles of 32 j = 128 j;
// block = 512 j; i chunked 72 x 128; K-steps of 16
#define CH 128
#define NKS 8             // CH/16
#define NIB 72            // i-chunks (grid.y)
#define JBX 18            // j-blocks (grid.x), 18*512=9216
#define NT 4

// rowsum tiling
#define RNI 144
#define RCH 64

// truncated separable gaussian: radius 24 (tail mass ~1.8e-4)
#define RAD2 24
#define TAPS2 49

typedef __attribute__((ext_vector_type(8))) short s8v;
typedef __attribute__((ext_vector_type(16))) float f16v;

// normalized separable 1D gaussian taps g[|d|] (exp(-d^2/72)/S, S=15.03977)
__device__ const float GN[36] = {
    6.64904e-02f, 6.55733e-02f, 6.28973e-02f, 5.86776e-02f, 5.32413e-02f,
    4.69853e-02f, 4.03286e-02f, 3.36665e-02f, 2.73351e-02f, 2.15863e-02f,
    1.65795e-02f, 1.23852e-02f, 8.99851e-03f, 6.35877e-03f, 4.37031e-03f,
    2.92139e-03f, 1.89933e-03f, 1.20102e-03f, 7.38645e-04f, 4.41830e-04f,
    2.57057e-04f, 1.45461e-04f, 8.00452e-05f, 4.28451e-05f, 2.23052e-05f,
    1.12939e-05f, 5.56182e-06f, 2.66396e-06f, 1.24101e-06f, 5.62291e-07f,
    2.47787e-07f, 1.06203e-07f, 4.42716e-08f, 1.79497e-08f, 7.07818e-09f,
    2.71479e-09f
};

__device__ __forceinline__ bool is_bf16(const void* kstd_raw){
    return (((const unsigned int*)kstd_raw)[0] & 0xFFFFu) != 0u;
}
__device__ __forceinline__ float ld_in(const void* p, int i, bool bf){
    if (bf){
        unsigned int u = ((unsigned int)((const unsigned short*)p)[i]) << 16;
        return __uint_as_float(u);
    }
    return ((const float*)p)[i];
}
__device__ __forceinline__ unsigned short f2bf(float f){
    unsigned int u = __float_as_uint(f);
    unsigned int r = u + 0x7FFFu + ((u >> 16) & 1u);   // RNE
    return (unsigned short)(r >> 16);
}

// ---------- setup: features (+|f|^2 in slot5), U=log(clip(u)), q0=softmax(U), zero qbf/nacc ----------
__global__ __launch_bounds__(256) void setup_kernel(const void* __restrict__ unary_raw,
                                                    const void* __restrict__ ref_raw,
                                                    const void* __restrict__ kstd_raw,
                                                    float* __restrict__ feat,
                                                    float* __restrict__ U, float* __restrict__ q,
                                                    float* __restrict__ qbf,
                                                    float* __restrict__ nacc){
    int i = blockIdx.x*256 + threadIdx.x;
    if (i >= NPX) return;
    bool bf = is_bf16(kstd_raw);
    const float SCL = 0.84932180028801907f; // sqrt(0.5*log2(e))
    int y = i / WW, x = i - y*WW;
    float f0 = (float)y * (SCL / ld_in(kstd_raw, 0, bf));
    float f1 = (float)x * (SCL / ld_in(kstd_raw, 1, bf));
    float f2 = ld_in(ref_raw, 0*NPX+i, bf) * (SCL / ld_in(kstd_raw, 2, bf));
    float f3 = ld_in(ref_raw, 1*NPX+i, bf) * (SCL / ld_in(kstd_raw, 3, bf));
    float f4 = ld_in(ref_raw, 2*NPX+i, bf) * (SCL / ld_in(kstd_raw, 4, bf));
    feat[i*8+0] = f0; feat[i*8+1] = f1; feat[i*8+2] = f2; feat[i*8+3] = f3; feat[i*8+4] = f4;
    feat[i*8+5] = f0*f0 + f1*f1 + f2*f2 + f3*f3 + f4*f4;
    feat[i*8+6] = 0.f; feat[i*8+7] = 0.f;
    nacc[i] = 0.f;

    float u[NC]; float m = -1e30f;
    #pragma unroll
    for (int c = 0; c < NC; ++c){
        float v = ld_in(unary_raw, c*NPX+i, bf);
        v = fminf(fmaxf(v, 1e-5f), 1.0f);
        float lg = logf(v);
        U[c*NPX+i] = lg;
        u[c] = lg;
        m = fmaxf(m, lg);
        qbf[c*NPX+i] = 0.f;
    }
    float s = 0.f;
    #pragma unroll
    for (int c = 0; c < NC; ++c){ u[c] = expf(u[c]-m); s += u[c]; }
    float inv = 1.f/s;
    #pragma unroll
    for (int c = 0; c < NC; ++c) q[c*NPX+i] = u[c]*inv;
}

// ---------- rowsum of K (for norm): -d2 = -sqj + (-sqi) + sum (2fi)*fj ----------
__global__ __launch_bounds__(256) void rowsum_kernel(const float* __restrict__ feat,
                                                     float* __restrict__ nacc){
    __shared__ __align__(16) float s_feat[RNI*8];
    int tid = threadIdx.x;
    int i0 = blockIdx.y * RNI;
    for (int s = tid; s < RNI*8; s += 256){
        float v = feat[i0*8 + s];
        int sl = s & 7;
        if (sl < 5) v *= 2.0f;
        else if (sl == 5) v = -v;
        s_feat[s] = v;
    }
    __syncthreads();
    int j = blockIdx.x*256 + tid;
    float4 fj = *(const float4*)(feat + j*8);
    float2 fj45 = *(const float2*)(feat + j*8 + 4);
    float fj4 = fj45.x, nsqj = -fj45.y;
    float a = 0.f;
    #pragma unroll 4
    for (int ii = 0; ii < RNI; ++ii){
        const float* sf = s_feat + ii*8;
        float4 f0 = *(const float4*)sf;
        float2 f45 = *(const float2*)(sf+4);
        float t = nsqj + f45.y;
        t = fmaf(fj.x, f0.x, t); t = fmaf(fj.y, f0.y, t); t = fmaf(fj.z, f0.z, t);
        t = fmaf(fj.w, f0.w, t); t = fmaf(fj4, f45.x, t);
        a += __builtin_amdgcn_exp2f(t);
    }
    atomicAdd(&nacc[j], a);
}

__global__ __launch_bounds__(256) void normfin_kernel(const float* __restrict__ nacc,
                                                      float* __restrict__ rnorm){
    int j = blockIdx.x*256 + threadIdx.x;
    if (j >= NPX) return;
    rnorm[j] = 1.0f / (sqrtf(nacc[j]) + 1e-8f);
}

// ---------- horizontal / vertical 1D gaussian conv (zero padded, radius 24) ----------
__global__ __launch_bounds__(256) void convh_kernel(const float* __restrict__ q,
                                                    float* __restrict__ o){
    int idx = blockIdx.x*256 + threadIdx.x;
    if (idx >= NC*NPX) return;
    int c = idx / NPX; int p = idx - c*NPX; int y = p / WW; int x = p - y*WW;
    const float* row = q + c*NPX + y*WW;
    int tlo = max(0, RAD2 - x);
    int thi = min(TAPS2-1, RAD2 + (WW-1) - x);
    float a = 0.f;
    for (int t = tlo; t <= thi; ++t) a += GN[abs(t-RAD2)]*row[x + t - RAD2];
    o[idx] = a;
}

__global__ __launch_bounds__(256) void convv_kernel(const float* __restrict__ q,
                                                    float* __restrict__ o){
    int idx = blockIdx.x*256 + threadIdx.x;
    if (idx >= NC*NPX) return;
    int c = idx / NPX; int p = idx - c*NPX; int y = p / WW; int x = p - y*WW;
    const float* col = q + c*NPX + x;
    int tlo = max(0, RAD2 - y);
    int thi = min(TAPS2-1, RAD2 + (HH-1) - y);
    float a = 0.f;
    for (int t = tlo; t <= thi; ++t) a += GN[abs(t-RAD2)]*col[(y + t - RAD2)*WW];
    o[idx] = a;
}

// ---------- dense bilateral via MFMA: qbf[c,j] += sum_i w(i,j) * tmp[c,i], w in bf16 ----------
__global__ __launch_bounds__(256) void bilateral_kernel(const float* __restrict__ q,
                                                        const float* __restrict__ feat,
                                                        const float* __restrict__ rnorm,
                                                        float* __restrict__ qbf){
    __shared__ __align__(16) float s_feat[CH*8];            // [2f0..2f4, -sq, pad, pad]
    __shared__ __align__(16) unsigned short s_tmpA[CH*32];  // [i>>3][c(32)][i&7] bf16
    int tid = threadIdx.x;
    int i0 = blockIdx.y * CH;
    for (int s = tid; s < CH*8; s += 256){
        float v = feat[(size_t)i0*8 + s];
        int sl = s & 7;
        if (sl < 5) v *= 2.0f;
        else if (sl == 5) v = -v;
        s_feat[s] = v;
    }
    for (int e = tid; e < 32*CH; e += 256){
        int c = e >> 7;            // e / CH (CH=128)
        int i = e & (CH-1);
        float val = (c < NC) ? q[c*NPX + i0 + i] * rnorm[i0 + i] : 0.f;
        s_tmpA[(i>>3)*256 + c*8 + (i&7)] = f2bf(val);
    }
    __syncthreads();

    int lane = tid & 63;
    int wv = tid >> 6;
    int jwb = blockIdx.x*512 + wv*128;
    int jl = lane & 31;
    int half = lane >> 5;

    float4 fj03[NT]; float fj4[NT], nsqj[NT];
    #pragma unroll
    for (int n = 0; n < NT; ++n){
        const float* fp = feat + (size_t)(jwb + n*32 + jl)*8;
        fj03[n] = *(const float4*)fp;
        float2 t = *(const float2*)(fp+4);
        fj4[n] = t.x; nsqj[n] = -t.y;
    }
    f16v acc[NT];
    #pragma unroll
    for (int n = 0; n < NT; ++n)
        #pragma unroll
        for (int r = 0; r < 16; ++r) acc[n][r] = 0.f;

    for (int kc = 0; kc < NKS; ++kc){
        s8v afrag = *(const s8v*)(s_tmpA + (kc*2 + half)*256 + jl*8);
        union { s8v v; __hip_bfloat162 h[4]; } bfr[NT];
        #pragma unroll
        for (int p = 0; p < 4; ++p){
            const float* sf0 = s_feat + (kc*16 + half*8 + p*2    )*8;
            const float* sf1 = s_feat + (kc*16 + half*8 + p*2 + 1)*8;
            float4 a03 = *(const float4*)sf0; float2 a45 = *(const float2*)(sf0+4);
            float4 b03 = *(const float4*)sf1; float2 b45 = *(const float2*)(sf1+4);
            #pragma unroll
            for (int n = 0; n < NT; ++n){
                float t0 = nsqj[n] + a45.y;
                t0 = fmaf(fj03[n].x, a03.x, t0); t0 = fmaf(fj03[n].y, a03.y, t0);
                t0 = fmaf(fj03[n].z, a03.z, t0); t0 = fmaf(fj03[n].w, a03.w, t0);
                t0 = fmaf(fj4[n],    a45.x, t0);
                float t1 = nsqj[n] + b45.y;
                t1 = fmaf(fj03[n].x, b03.x, t1); t1 = fmaf(fj03[n].y, b03.y, t1);
                t1 = fmaf(fj03[n].z, b03.z, t1); t1 = fmaf(fj03[n].w, b03.w, t1);
                t1 = fmaf(fj4[n],    b45.x, t1);
                float w0 = __builtin_amdgcn_exp2f(t0);
                float w1 = __builtin_amdgcn_exp2f(t1);
                bfr[n].h[p] = __float22bfloat162_rn(make_float2(w0, w1));
            }
        }
        #pragma unroll
        for (int n = 0; n < NT; ++n)
            acc[n] = __builtin_amdgcn_mfma_f32_32x32x16_bf16(afrag, bfr[n].v, acc[n], 0, 0, 0);
    }
    // C layout: col=j=lane&31, row=c=(reg&3)+8*(reg>>2)+4*(lane>>5)
    #pragma unroll
    for (int n = 0; n < NT; ++n){
        int j = jwb + n*32 + jl;
        #pragma unroll
        for (int r = 0; r < 16; ++r){
            int c = (r&3) + 8*(r>>2) + 4*half;
            if (c < NC) atomicAdd(&qbf[c*NPX + j], acc[n][r]);
        }
    }
}

// ---------- q_hat = U + 4*qbf*rnorm_j + 2*qsf ; softmax; zero qbf for next iter ----------
__global__ __launch_bounds__(256) void combine_kernel(const float* __restrict__ U,
                                                      float* __restrict__ qbf,
                                                      const float* __restrict__ qsf,
                                                      const float* __restrict__ rnorm,
                                                      float* __restrict__ qn,
                                                      void* __restrict__ outp,
                                                      const void* __restrict__ kstd_raw){
    int j = blockIdx.x*256 + threadIdx.x;
    if (j >= NPX) return;
    float rn = rnorm[j];
    float h[NC]; float m = -1e30f;
    #pragma unroll
    for (int c = 0; c < NC; ++c){
        float v = U[c*NPX+j] + 4.0f*qbf[c*NPX+j]*rn + 2.0f*qsf[c*NPX+j];
        qbf[c*NPX+j] = 0.f;
        h[c] = v; m = fmaxf(m, v);
    }
    float s = 0.f;
    #pragma unroll
    for (int c = 0; c < NC; ++c){ h[c] = expf(h[c]-m); s += h[c]; }
    float inv = 1.f/s;
    bool bf = outp ? is_bf16(kstd_raw) : false;
    #pragma unroll
    for (int c = 0; c < NC; ++c){
        float v = h[c]*inv;
        qn[c*NPX+j] = v;
        if (outp){
            if (bf) ((__hip_bfloat16*)outp)[c*NPX+j] = __float2bfloat16(v);
            else    ((float*)outp)[c*NPX+j] = v;
        }
    }
}

extern "C" void kernel_launch(void* const* d_in, const int* in_sizes, int n_in,
                              void* d_out, int out_size, void* d_ws, size_t ws_size,
                              hipStream_t stream) {
    const void* unary_raw = d_in[0];
    const void* ref_raw   = d_in[1];
    const void* kstd_raw  = d_in[2];

    float* w = (float*)d_ws;
    float* feat  = w; w += NPX*8;
    float* U     = w; w += NC*NPX;
    float* qA    = w; w += NC*NPX;
    float* qB    = w; w += NC*NPX;
    float* t1b   = w; w += NC*NPX;
    float* qsf   = w; w += NC*NPX;
    float* qbf   = w; w += NC*NPX;
    float* nacc  = w; w += NPX;
    float* rnorm = w; w += NPX;

    hipLaunchKernelGGL(setup_kernel, dim3(36), dim3(256), 0, stream,
                       unary_raw, ref_raw, kstd_raw, feat, U, qA, qbf, nacc);
    hipLaunchKernelGGL(rowsum_kernel, dim3(36, RCH), dim3(256), 0, stream, feat, nacc);
    hipLaunchKernelGGL(normfin_kernel, dim3(36), dim3(256), 0, stream, nacc, rnorm);

    float* qc = qA; float* qn = qB;
    for (int it = 0; it < 5; ++it){
        hipLaunchKernelGGL(convh_kernel, dim3(756), dim3(256), 0, stream, qc, t1b);
        hipLaunchKernelGGL(convv_kernel, dim3(756), dim3(256), 0, stream, t1b, qsf);
        hipLaunchKernelGGL(bilateral_kernel, dim3(JBX, NIB), dim3(256), 0, stream, qc, feat, rnorm, qbf);
        hipLaunchKernelGGL(combine_kernel, dim3(36), dim3(256), 0, stream,
                           U, qbf, qsf, rnorm, qn, (it == 4) ? d_out : (void*)nullptr, kstd_raw);
        float* tswap = qc; qc = qn; qn = tswap;
    }
}

// Round 7
// 422.111 us; speedup vs baseline: 4.5657x; 1.2683x over previous
//
#include <hip/hip_runtime.h>
#include <hip/hip_bf16.h>

#define HH 96
#define WW 96
#define NPX 9216          // HH*WW
#define NC 21             // classes

// bilateral MFMA tiling: block=256 (4 waves); wave = 2 n-tiles of 32 j = 64 j;
// block = 256 j; grid (36 j-blocks, 36 i-chunks of 256); K-steps of 16
#define CH 256
#define NKS 16            // CH/16
#define NCHK 36           // i-chunks (grid.y)
#define JBX 36            // j-blocks (grid.x), 36*256=9216
#define NT 2

// rowsum tiling
#define RNI 144
#define RCH 64

// truncated separable gaussian: radius 24 (tail mass ~1.8e-4)
#define RAD2 24
#define TAPS2 49

typedef __attribute__((ext_vector_type(8))) short s8v;
typedef __attribute__((ext_vector_type(16))) float f16v;

// normalized separable 1D gaussian taps g[|d|] (exp(-d^2/72)/S, S=15.03977)
__device__ const float GN[36] = {
    6.64904e-02f, 6.55733e-02f, 6.28973e-02f, 5.86776e-02f, 5.32413e-02f,
    4.69853e-02f, 4.03286e-02f, 3.36665e-02f, 2.73351e-02f, 2.15863e-02f,
    1.65795e-02f, 1.23852e-02f, 8.99851e-03f, 6.35877e-03f, 4.37031e-03f,
    2.92139e-03f, 1.89933e-03f, 1.20102e-03f, 7.38645e-04f, 4.41830e-04f,
    2.57057e-04f, 1.45461e-04f, 8.00452e-05f, 4.28451e-05f, 2.23052e-05f,
    1.12939e-05f, 5.56182e-06f, 2.66396e-06f, 1.24101e-06f, 5.62291e-07f,
    2.47787e-07f, 1.06203e-07f, 4.42716e-08f, 1.79497e-08f, 7.07818e-09f,
    2.71479e-09f
};

__device__ __forceinline__ bool is_bf16(const void* kstd_raw){
    return (((const unsigned int*)kstd_raw)[0] & 0xFFFFu) != 0u;
}
__device__ __forceinline__ float ld_in(const void* p, int i, bool bf){
    if (bf){
        unsigned int u = ((unsigned int)((const unsigned short*)p)[i]) << 16;
        return __uint_as_float(u);
    }
    return ((const float*)p)[i];
}
__device__ __forceinline__ unsigned short f2bf(float f){
    unsigned int u = __float_as_uint(f);
    unsigned int r = u + 0x7FFFu + ((u >> 16) & 1u);   // RNE
    return (unsigned short)(r >> 16);
}

// ---------- setup: features (+|f|^2 in slot5), U=log(clip(u)), q0=softmax(U), zero qbf/nacc ----------
__global__ __launch_bounds__(256) void setup_kernel(const void* __restrict__ unary_raw,
                                                    const void* __restrict__ ref_raw,
                                                    const void* __restrict__ kstd_raw,
                                                    float* __restrict__ feat,
                                                    float* __restrict__ U, float* __restrict__ q,
                                                    float* __restrict__ qbf,
                                                    float* __restrict__ nacc){
    int i = blockIdx.x*256 + threadIdx.x;
    if (i >= NPX) return;
    bool bf = is_bf16(kstd_raw);
    const float SCL = 0.84932180028801907f; // sqrt(0.5*log2(e))
    int y = i / WW, x = i - y*WW;
    float f0 = (float)y * (SCL / ld_in(kstd_raw, 0, bf));
    float f1 = (float)x * (SCL / ld_in(kstd_raw, 1, bf));
    float f2 = ld_in(ref_raw, 0*NPX+i, bf) * (SCL / ld_in(kstd_raw, 2, bf));
    float f3 = ld_in(ref_raw, 1*NPX+i, bf) * (SCL / ld_in(kstd_raw, 3, bf));
    float f4 = ld_in(ref_raw, 2*NPX+i, bf) * (SCL / ld_in(kstd_raw, 4, bf));
    feat[i*8+0] = f0; feat[i*8+1] = f1; feat[i*8+2] = f2; feat[i*8+3] = f3; feat[i*8+4] = f4;
    feat[i*8+5] = f0*f0 + f1*f1 + f2*f2 + f3*f3 + f4*f4;
    feat[i*8+6] = 0.f; feat[i*8+7] = 0.f;
    nacc[i] = 0.f;

    float u[NC]; float m = -1e30f;
    #pragma unroll
    for (int c = 0; c < NC; ++c){
        float v = ld_in(unary_raw, c*NPX+i, bf);
        v = fminf(fmaxf(v, 1e-5f), 1.0f);
        float lg = logf(v);
        U[c*NPX+i] = lg;
        u[c] = lg;
        m = fmaxf(m, lg);
        qbf[c*NPX+i] = 0.f;
    }
    float s = 0.f;
    #pragma unroll
    for (int c = 0; c < NC; ++c){ u[c] = expf(u[c]-m); s += u[c]; }
    float inv = 1.f/s;
    #pragma unroll
    for (int c = 0; c < NC; ++c) q[c*NPX+i] = u[c]*inv;
}

// ---------- rowsum of K (for norm): -d2 = -sqj + (-sqi) + sum (2fi)*fj ----------
__global__ __launch_bounds__(256) void rowsum_kernel(const float* __restrict__ feat,
                                                     float* __restrict__ nacc){
    __shared__ __align__(16) float s_feat[RNI*8];
    int tid = threadIdx.x;
    int i0 = blockIdx.y * RNI;
    for (int s = tid; s < RNI*8; s += 256){
        float v = feat[i0*8 + s];
        int sl = s & 7;
        if (sl < 5) v *= 2.0f;
        else if (sl == 5) v = -v;
        s_feat[s] = v;
    }
    __syncthreads();
    int j = blockIdx.x*256 + tid;
    float4 fj = *(const float4*)(feat + j*8);
    float2 fj45 = *(const float2*)(feat + j*8 + 4);
    float fj4 = fj45.x, nsqj = -fj45.y;
    float a = 0.f;
    #pragma unroll 4
    for (int ii = 0; ii < RNI; ++ii){
        const float* sf = s_feat + ii*8;
        float4 f0 = *(const float4*)sf;
        float2 f45 = *(const float2*)(sf+4);
        float t = nsqj + f45.y;
        t = fmaf(fj.x, f0.x, t); t = fmaf(fj.y, f0.y, t); t = fmaf(fj.z, f0.z, t);
        t = fmaf(fj.w, f0.w, t); t = fmaf(fj4, f45.x, t);
        a += __builtin_amdgcn_exp2f(t);
    }
    atomicAdd(&nacc[j], a);
}

__global__ __launch_bounds__(256) void normfin_kernel(const float* __restrict__ nacc,
                                                      float* __restrict__ rnorm){
    int j = blockIdx.x*256 + threadIdx.x;
    if (j >= NPX) return;
    rnorm[j] = 1.0f / (sqrtf(nacc[j]) + 1e-8f);
}

// ---------- horizontal / vertical 1D gaussian conv (zero padded, radius 24) ----------
__global__ __launch_bounds__(256) void convh_kernel(const float* __restrict__ q,
                                                    float* __restrict__ o){
    int idx = blockIdx.x*256 + threadIdx.x;
    if (idx >= NC*NPX) return;
    int c = idx / NPX; int p = idx - c*NPX; int y = p / WW; int x = p - y*WW;
    const float* row = q + c*NPX + y*WW;
    int tlo = max(0, RAD2 - x);
    int thi = min(TAPS2-1, RAD2 + (WW-1) - x);
    float a = 0.f;
    for (int t = tlo; t <= thi; ++t) a += GN[abs(t-RAD2)]*row[x + t - RAD2];
    o[idx] = a;
}

__global__ __launch_bounds__(256) void convv_kernel(const float* __restrict__ q,
                                                    float* __restrict__ o){
    int idx = blockIdx.x*256 + threadIdx.x;
    if (idx >= NC*NPX) return;
    int c = idx / NPX; int p = idx - c*NPX; int y = p / WW; int x = p - y*WW;
    const float* col = q + c*NPX + x;
    int tlo = max(0, RAD2 - y);
    int thi = min(TAPS2-1, RAD2 + (HH-1) - y);
    float a = 0.f;
    for (int t = tlo; t <= thi; ++t) a += GN[abs(t-RAD2)]*col[(y + t - RAD2)*WW];
    o[idx] = a;
}

// ---------- dense bilateral via MFMA: partial[c,j] = sum_{i in chunk} w(i,j)*tmp[c,i] ----------
__global__ __launch_bounds__(256) void bilateral_kernel(const float* __restrict__ q,
                                                        const float* __restrict__ feat,
                                                        const float* __restrict__ rnorm,
                                                        float* __restrict__ qbf,
                                                        float* __restrict__ part,
                                                        int use_part){
    __shared__ __align__(16) float s_feat[CH*8];            // [2f0..2f4, -sq, pad, pad]
    __shared__ __align__(16) unsigned short s_tmpA[CH*32];  // [i>>3][c(32)][i&7] bf16
    int tid = threadIdx.x;
    int i0 = blockIdx.y * CH;
    for (int s = tid; s < CH*8; s += 256){
        float v = feat[(size_t)i0*8 + s];
        int sl = s & 7;
        if (sl < 5) v *= 2.0f;
        else if (sl == 5) v = -v;
        s_feat[s] = v;
    }
    for (int e = tid; e < 32*CH; e += 256){
        int c = e >> 8;            // e / CH (CH=256)
        int i = e & (CH-1);
        float val = (c < NC) ? q[c*NPX + i0 + i] * rnorm[i0 + i] : 0.f;
        s_tmpA[(i>>3)*256 + c*8 + (i&7)] = f2bf(val);
    }
    __syncthreads();

    int lane = tid & 63;
    int wv = tid >> 6;
    int jwb = blockIdx.x*256 + wv*64;
    int jl = lane & 31;
    int half = lane >> 5;

    float4 fj03[NT]; float fj4[NT], nsqj[NT];
    #pragma unroll
    for (int n = 0; n < NT; ++n){
        const float* fp = feat + (size_t)(jwb + n*32 + jl)*8;
        fj03[n] = *(const float4*)fp;
        float2 t = *(const float2*)(fp+4);
        fj4[n] = t.x; nsqj[n] = -t.y;
    }
    f16v acc[NT];
    #pragma unroll
    for (int n = 0; n < NT; ++n)
        #pragma unroll
        for (int r = 0; r < 16; ++r) acc[n][r] = 0.f;

    for (int kc = 0; kc < NKS; ++kc){
        s8v afrag = *(const s8v*)(s_tmpA + (kc*2 + half)*256 + jl*8);
        union { s8v v; __hip_bfloat162 h[4]; } bfr[NT];
        #pragma unroll
        for (int p = 0; p < 4; ++p){
            const float* sf0 = s_feat + (kc*16 + half*8 + p*2    )*8;
            const float* sf1 = s_feat + (kc*16 + half*8 + p*2 + 1)*8;
            float4 a03 = *(const float4*)sf0; float2 a45 = *(const float2*)(sf0+4);
            float4 b03 = *(const float4*)sf1; float2 b45 = *(const float2*)(sf1+4);
            #pragma unroll
            for (int n = 0; n < NT; ++n){
                float t0 = nsqj[n] + a45.y;
                t0 = fmaf(fj03[n].x, a03.x, t0); t0 = fmaf(fj03[n].y, a03.y, t0);
                t0 = fmaf(fj03[n].z, a03.z, t0); t0 = fmaf(fj03[n].w, a03.w, t0);
                t0 = fmaf(fj4[n],    a45.x, t0);
                float t1 = nsqj[n] + b45.y;
                t1 = fmaf(fj03[n].x, b03.x, t1); t1 = fmaf(fj03[n].y, b03.y, t1);
                t1 = fmaf(fj03[n].z, b03.z, t1); t1 = fmaf(fj03[n].w, b03.w, t1);
                t1 = fmaf(fj4[n],    b45.x, t1);
                float w0 = __builtin_amdgcn_exp2f(t0);
                float w1 = __builtin_amdgcn_exp2f(t1);
                bfr[n].h[p] = __float22bfloat162_rn(make_float2(w0, w1));
            }
        }
        #pragma unroll
        for (int n = 0; n < NT; ++n)
            acc[n] = __builtin_amdgcn_mfma_f32_32x32x16_bf16(afrag, bfr[n].v, acc[n], 0, 0, 0);
    }
    // C layout: col=j=lane&31, row=c=(reg&3)+8*(reg>>2)+4*(lane>>5)
    if (use_part){
        float* dst = part + (size_t)blockIdx.y * (NC*NPX);
        #pragma unroll
        for (int n = 0; n < NT; ++n){
            int j = jwb + n*32 + jl;
            #pragma unroll
            for (int r = 0; r < 16; ++r){
                int c = (r&3) + 8*(r>>2) + 4*half;
                if (c < NC) dst[c*NPX + j] = acc[n][r];
            }
        }
    } else {
        #pragma unroll
        for (int n = 0; n < NT; ++n){
            int j = jwb + n*32 + jl;
            #pragma unroll
            for (int r = 0; r < 16; ++r){
                int c = (r&3) + 8*(r>>2) + 4*half;
                if (c < NC) atomicAdd(&qbf[c*NPX + j], acc[n][r]);
            }
        }
    }
}

// ---------- sum the 36 chunk-partials into qbf ----------
__global__ __launch_bounds__(256) void reduce_kernel(const float* __restrict__ part,
                                                     float* __restrict__ qbf){
    int idx = blockIdx.x*256 + threadIdx.x;
    if (idx >= NC*NPX) return;
    float s = 0.f;
    #pragma unroll
    for (int ch = 0; ch < NCHK; ++ch) s += part[(size_t)ch*(NC*NPX) + idx];
    qbf[idx] = s;
}

// ---------- q_hat = U + 4*qbf*rnorm_j + 2*qsf ; softmax; zero qbf for next iter ----------
__global__ __launch_bounds__(256) void combine_kernel(const float* __restrict__ U,
                                                      float* __restrict__ qbf,
                                                      const float* __restrict__ qsf,
                                                      const float* __restrict__ rnorm,
                                                      float* __restrict__ qn,
                                                      void* __restrict__ outp,
                                                      const void* __restrict__ kstd_raw){
    int j = blockIdx.x*256 + threadIdx.x;
    if (j >= NPX) return;
    float rn = rnorm[j];
    float h[NC]; float m = -1e30f;
    #pragma unroll
    for (int c = 0; c < NC; ++c){
        float v = U[c*NPX+j] + 4.0f*qbf[c*NPX+j]*rn + 2.0f*qsf[c*NPX+j];
        qbf[c*NPX+j] = 0.f;
        h[c] = v; m = fmaxf(m, v);
    }
    float s = 0.f;
    #pragma unroll
    for (int c = 0; c < NC; ++c){ h[c] = expf(h[c]-m); s += h[c]; }
    float inv = 1.f/s;
    bool bf = outp ? is_bf16(kstd_raw) : false;
    #pragma unroll
    for (int c = 0; c < NC; ++c){
        float v = h[c]*inv;
        qn[c*NPX+j] = v;
        if (outp){
            if (bf) ((__hip_bfloat16*)outp)[c*NPX+j] = __float2bfloat16(v);
            else    ((float*)outp)[c*NPX+j] = v;
        }
    }
}

extern "C" void kernel_launch(void* const* d_in, const int* in_sizes, int n_in,
                              void* d_out, int out_size, void* d_ws, size_t ws_size,
                              hipStream_t stream) {
    const void* unary_raw = d_in[0];
    const void* ref_raw   = d_in[1];
    const void* kstd_raw  = d_in[2];

    float* w = (float*)d_ws;
    float* feat  = w; w += NPX*8;
    float* U     = w; w += NC*NPX;
    float* qA    = w; w += NC*NPX;
    float* qB    = w; w += NC*NPX;
    float* t1b   = w; w += NC*NPX;
    float* qsf   = w; w += NC*NPX;
    float* qbf   = w; w += NC*NPX;
    float* nacc  = w; w += NPX;
    float* rnorm = w; w += NPX;
    float* part  = w; w += (size_t)NCHK*NC*NPX;

    // partial-sum path needs ~32.2 MB of workspace; ws_size is launch-constant,
    // so this branch is identical every call (graph-capture safe).
    size_t need = (size_t)((char*)w - (char*)d_ws);
    int use_part = (ws_size >= need) ? 1 : 0;

    hipLaunchKernelGGL(setup_kernel, dim3(36), dim3(256), 0, stream,
                       unary_raw, ref_raw, kstd_raw, feat, U, qA, qbf, nacc);
    hipLaunchKernelGGL(rowsum_kernel, dim3(36, RCH), dim3(256), 0, stream, feat, nacc);
    hipLaunchKernelGGL(normfin_kernel, dim3(36), dim3(256), 0, stream, nacc, rnorm);

    float* qc = qA; float* qn = qB;
    for (int it = 0; it < 5; ++it){
        hipLaunchKernelGGL(convh_kernel, dim3(756), dim3(256), 0, stream, qc, t1b);
        hipLaunchKernelGGL(convv_kernel, dim3(756), dim3(256), 0, stream, t1b, qsf);
        hipLaunchKernelGGL(bilateral_kernel, dim3(JBX, NCHK), dim3(256), 0, stream,
                           qc, feat, rnorm, qbf, part, use_part);
        if (use_part)
            hipLaunchKernelGGL(reduce_kernel, dim3(756), dim3(256), 0, stream, part, qbf);
        hipLaunchKernelGGL(combine_kernel, dim3(36), dim3(256), 0, stream,
                           U, qbf, qsf, rnorm, qn, (it == 4) ? d_out : (void*)nullptr, kstd_raw);
        float* tswap = qc; qc = qn; qn = tswap;
    }
}